// Round 9
// baseline (229.327 us; speedup 1.0000x reference)
//
#include <hip/hip_runtime.h>
#include <math.h>

#define B_DIM 2
#define S_DIM 2048
#define D_DIM 1024
#define H_NUM 16
#define DH    64
#define M_DIM (B_DIM * S_DIM) /* 4096 */

typedef __attribute__((ext_vector_type(8))) short short8;
typedef __attribute__((ext_vector_type(4))) short short4v;
typedef __attribute__((ext_vector_type(4))) float float4v;
typedef __attribute__((ext_vector_type(4))) unsigned short ushort4v;
typedef unsigned short ushort;

static __device__ __forceinline__ ushort f2bf(float f) {
    unsigned u = __float_as_uint(f);
    u += 0x7fffu + ((u >> 16) & 1u);
    return (ushort)(u >> 16);
}

static __device__ __forceinline__ float fexp2(float x) {
#if __has_builtin(__builtin_amdgcn_exp2f)
    return __builtin_amdgcn_exp2f(x);
#else
    return exp2f(x);
#endif
}

// 2 f32 -> 2 bf16 in one u32, lo half = first arg. Ordering PROVEN on this
// harness (rounds 3/4 bit-identical).
static __device__ __forceinline__ unsigned cvtpk_bf16(float lo, float hi) {
    unsigned r;
    asm("v_cvt_pk_bf16_f32 %0, %1, %2" : "=v"(r) : "v"(lo), "v"(hi));
    return r;
}

static __device__ __forceinline__ void gload_lds16(const void* g, void* l) {
    __builtin_amdgcn_global_load_lds(
        (const __attribute__((address_space(1))) void*)g,
        (__attribute__((address_space(3))) void*)l, 16, 0, 0);
}

// ---------------------------------------------------------------------------
// Fused fp32 -> bf16 cast of ALL five tensors in one launch.
// dst layout (contiguous in ws): xh[4M] | wq[1M] | wk[1M] | wv[1M] | wo[1M]
// ---------------------------------------------------------------------------
__global__ __launch_bounds__(256)
void cast_all(const float* __restrict__ x,  const float* __restrict__ wq,
              const float* __restrict__ wk, const float* __restrict__ wv,
              const float* __restrict__ wo, ushort* __restrict__ dst)
{
    const int i = blockIdx.x * 256 + threadIdx.x;   // 0 .. 2M-1 (float4 units)
    const float4* s;
    int off;
    if      (i < 1048576) { s = (const float4*)x;  off = 0;       }
    else if (i < 1310720) { s = (const float4*)wq; off = 1048576; }
    else if (i < 1572864) { s = (const float4*)wk; off = 1310720; }
    else if (i < 1835008) { s = (const float4*)wv; off = 1572864; }
    else                  { s = (const float4*)wo; off = 1835008; }
    const float4 v = s[i - off];
    ushort4v o;
    o[0] = f2bf(v.x); o[1] = f2bf(v.y); o[2] = f2bf(v.z); o[3] = f2bf(v.w);
    ((ushort4v*)dst)[i] = o;
}

// ---------------------------------------------------------------------------
// bf16 MFMA GEMM, m97 structure: 128x128 tile, BK=32, global_load_lds w=16,
// 4 waves in 2x2, each wave 64x64 via 4x4 grid of 16x16x32 MFMAs.
// A:[M=4096, K=1024] bf16 row-major. B:[N, K=1024] bf16 row-major.
// mode 0 (N=3072, fused QKV): n>>10 selects dst: 0->Qh [B,H,S,Dh]
//        (PRE-SCALED by 0.125*log2e for base-2 online softmax),
//        1->Kh [B,H,S,Dh], 2->Vt [B,H,Dh,S]; all bf16.
// mode 1 (N=1024, out proj): fp32 out[m*1024+n] = acc + bias[n].
// ---------------------------------------------------------------------------
__global__ __launch_bounds__(256)
void gemm_bf16(const ushort* __restrict__ A, const ushort* __restrict__ B,
               ushort* __restrict__ Qh, ushort* __restrict__ Kh,
               ushort* __restrict__ Vt, float* __restrict__ Of,
               const float* __restrict__ bias, int mode)
{
    __shared__ ushort Asm[128 * 32];   // [row][k], 64B rows, lane-order (no pad!)
    __shared__ ushort Bsm[128 * 32];

    const int K  = 1024;
    const int n0 = blockIdx.x * 128;
    const int m0 = blockIdx.y * 128;
    const int t    = threadIdx.x;
    const int w    = t >> 6;
    const int lane = t & 63;
    const int n    = lane & 15;
    const int quad = lane >> 4;
    const int wm = w >> 1, wn = w & 1;

    const int srow = w * 32 + (lane >> 2);
    const int skel = (lane & 3) * 8;

    float4v acc[4][4];
#pragma unroll
    for (int mt = 0; mt < 4; ++mt)
#pragma unroll
        for (int nt = 0; nt < 4; ++nt) acc[mt][nt] = (float4v){0.f, 0.f, 0.f, 0.f};

    for (int kt = 0; kt < K; kt += 32) {
#pragma unroll
        for (int i = 0; i < 2; ++i) {
            gload_lds16(&A[(size_t)(m0 + srow + i * 16) * K + kt + skel],
                        &Asm[(w * 2 + i) * 512]);
            gload_lds16(&B[(size_t)(n0 + srow + i * 16) * K + kt + skel],
                        &Bsm[(w * 2 + i) * 512]);
        }
        __syncthreads();

        short8 af[4], bfr[4];
#pragma unroll
        for (int mt = 0; mt < 4; ++mt)
            af[mt] = *(const short8*)&Asm[(wm * 64 + mt * 16 + n) * 32 + quad * 8];
#pragma unroll
        for (int nt = 0; nt < 4; ++nt)
            bfr[nt] = *(const short8*)&Bsm[(wn * 64 + nt * 16 + n) * 32 + quad * 8];

#pragma unroll
        for (int mt = 0; mt < 4; ++mt)
#pragma unroll
            for (int nt = 0; nt < 4; ++nt)
                acc[mt][nt] = __builtin_amdgcn_mfma_f32_16x16x32_bf16(
                    af[mt], bfr[nt], acc[mt][nt], 0, 0, 0);
        __syncthreads();
    }

    if (mode == 0) {
        const int wid = n0 >> 10;           // 0=Q 1=K 2=V (constant per block)
        ushort* dstQK = (wid == 0) ? Qh : Kh;
        const float qs = (wid == 0) ? 0.1803368801f : 1.0f;  // 0.125*log2(e)
#pragma unroll
        for (int mt = 0; mt < 4; ++mt) {
            const int m = m0 + wm * 64 + mt * 16 + quad * 4;   // +r
            const int b = m >> 11, s = m & (S_DIM - 1);
#pragma unroll
            for (int nt = 0; nt < 4; ++nt) {
                const int ng = (n0 & 1023) + wn * 64 + nt * 16 + n;
                const int h = ng >> 6, d = ng & 63;
                const int bh = b * H_NUM + h;
                if (wid < 2) {
#pragma unroll
                    for (int r = 0; r < 4; ++r)
                        dstQK[(((size_t)bh * S_DIM + s + r) << 6) + d] =
                            f2bf(acc[mt][nt][r] * qs);
                } else {
                    ushort4v p;
#pragma unroll
                    for (int r = 0; r < 4; ++r) p[r] = f2bf(acc[mt][nt][r]);
                    *(ushort4v*)&Vt[(((size_t)bh * DH + d) << 11) + s] = p;
                }
            }
        }
    } else {
#pragma unroll
        for (int mt = 0; mt < 4; ++mt) {
            const int m = m0 + wm * 64 + mt * 16 + quad * 4;
#pragma unroll
            for (int nt = 0; nt < 4; ++nt) {
                const int ng = n0 + wn * 64 + nt * 16 + n;
                const float bv = bias[ng];
#pragma unroll
                for (int r = 0; r < 4; ++r)
                    Of[(size_t)(m + r) * D_DIM + ng] = acc[mt][nt][r] + bv;
            }
        }
    }
}

// ---------------------------------------------------------------------------
// MFMA flash attention: 64 q-rows/wave, 2-wave blocks (128 thr), grid 512.
// Rationale (round-7 counters): kernel was LDS-byte-bound -- per kb each
// wave reads the full 16KB K+V fragment set regardless of its Q-rows, so
// per-CU LDS traffic = waves/CU * 16KB. Doubling q-rows/wave halves wave
// count: LDS/CU/kb 160KB -> 96KB with VALU & MFMA per CU invariant.
// 2 blocks/CU stagger barriers/staging to keep pipes fed at 1 wave/SIMD.
// Swapped QK^T, fully LOCAL P->PV handoff via the k-slot->key remap
// slot q*8+e <-> key 32kc+16(e>>2)+4q+(e&3) (A and B use the same map).
// Defer-max (THR=8, base-2); Q pre-scaled by 0.125*log2e; cvt_pk packing.
// ---------------------------------------------------------------------------
__global__ __launch_bounds__(128)
void attn_mfma(const ushort* __restrict__ Qh, const ushort* __restrict__ Kh,
               const ushort* __restrict__ Vt, ushort* __restrict__ Yh)
{
    __shared__ ushort Ksm[2][64 * 64];   // [buf][key 64][d 64] granule-swizzled
    __shared__ ushort Vsm[2][64 * 64];   // [buf][d 64][key 64] granule-swizzled

    const int w    = threadIdx.x >> 6;   // 0..1
    const int lane = threadIdx.x & 63;
    const int n    = lane & 15;
    const int quad = lane >> 4;

    const int wave_id = blockIdx.x * 2 + w;
    const int bh    = wave_id >> 5;          // both waves of a block: same bh
    const int qbase = (wave_id & 31) * 64;
    const int b     = bh >> 4;
    const int h     = bh & (H_NUM - 1);

    const ushort* Qb = Qh + (((size_t)bh * S_DIM) << 6);
    const ushort* Kb = Kh + (((size_t)bh * S_DIM) << 6);
    const ushort* Vb = Vt + (((size_t)bh * DH) << 11);

    // staging: each wave covers 32 rows (4 iters x 8 rows); lane l covers row
    // sub-index l>>3, 16B granule (l&7), source granule pre-swizzled
    // (gload_lds dst must stay linear).
    const int l8 = lane >> 3;
    const int sg = (lane & 7) ^ l8;

    short8 qa[4][2];   // B-frag: lane holds Q[q = mt*16+n][d = kc*32+quad*8 ..]
#pragma unroll
    for (int mt = 0; mt < 4; ++mt)
#pragma unroll
        for (int kc = 0; kc < 2; ++kc)
            qa[mt][kc] = *(const short8*)&Qb[((size_t)(qbase + mt * 16 + n) << 6) + kc * 32 + quad * 8];

    float4v O[4][4];           // O[mt][nt][r]: q = mt*16+quad*4+r, d = nt*16+n
    float   mrow[4], lrow[4];  // per-lane: q = mt*16 + n (uniform over quads)
#pragma unroll
    for (int mt = 0; mt < 4; ++mt) {
#pragma unroll
        for (int nt = 0; nt < 4; ++nt) O[mt][nt] = (float4v){0.f, 0.f, 0.f, 0.f};
        mrow[mt] = -1e30f; lrow[mt] = 0.f;
    }

    // K fragment-read offsets (ushort units): logical granule g at row rr is
    // stored at physical g ^ (rr&7); rr&7 == n&7 for rr = ct*16 + n.
    const int fswz[2] = { ((0 * 4 + quad) ^ (n & 7)) * 8,
                          ((1 * 4 + quad) ^ (n & 7)) * 8 };
    // V b64 read offsets for the slot-key remap: for kc, cc: logical granule
    // 4kc + 2cc + (quad>>1), half (quad&1); physical = logical ^ (n&7).
    const int h4 = (quad & 1) * 4;
    const int q2 = quad >> 1;
    int vswz[2][2];
#pragma unroll
    for (int kc = 0; kc < 2; ++kc)
#pragma unroll
        for (int cc = 0; cc < 2; ++cc)
            vswz[kc][cc] = (((4 * kc + 2 * cc + q2) ^ (n & 7)) << 3) + h4;

    // prologue: stage tile 0 into buffer 0 (each wave 32 rows of K and V)
#pragma unroll
    for (int i = 0; i < 4; ++i) {
        gload_lds16(&Kb[(size_t)(w * 32 + i * 8 + l8) * 64 + sg * 8],
                    &Ksm[0][(w * 32 + i * 8) * 64]);
        gload_lds16(&Vb[(size_t)(w * 32 + i * 8 + l8) * 2048 + sg * 8],
                    &Vsm[0][(w * 32 + i * 8) * 64]);
    }

    for (int kb = 0; kb < S_DIM / 64; ++kb) {
        __syncthreads();   // stage(kb) complete; buf cur^1 free for overwrite
        const int cur = kb & 1;
        if (kb + 1 < S_DIM / 64) {
            const int key1 = (kb + 1) * 64;
            const int nxt  = cur ^ 1;
#pragma unroll
            for (int i = 0; i < 4; ++i) {
                gload_lds16(&Kb[(size_t)(key1 + w * 32 + i * 8 + l8) * 64 + sg * 8],
                            &Ksm[nxt][(w * 32 + i * 8) * 64]);
                gload_lds16(&Vb[(size_t)(w * 32 + i * 8 + l8) * 2048 + key1 + sg * 8],
                            &Vsm[nxt][(w * 32 + i * 8) * 64]);
            }
        }

        // A-frag: lane holds K[key = ct*16+n][d = kc*32+quad*8 ..]
        short8 kf[4][2];
#pragma unroll
        for (int ct = 0; ct < 4; ++ct)
#pragma unroll
            for (int kc = 0; kc < 2; ++kc)
                kf[ct][kc] = *(const short8*)&Ksm[cur][(ct * 16 + n) * 64 + fswz[kc]];

        // S^T[key][q]: s[mt][ct][r] = S[q = mt*16+n][key = ct*16+quad*4+r]
        float4v s[4][4];
        __builtin_amdgcn_s_setprio(1);
#pragma unroll
        for (int mt = 0; mt < 4; ++mt)
#pragma unroll
            for (int ct = 0; ct < 4; ++ct) {
                float4v a = (float4v){0.f, 0.f, 0.f, 0.f};
                a = __builtin_amdgcn_mfma_f32_16x16x32_bf16(kf[ct][0], qa[mt][0], a, 0, 0, 0);
                a = __builtin_amdgcn_mfma_f32_16x16x32_bf16(kf[ct][1], qa[mt][1], a, 0, 0, 0);
                s[mt][ct] = a;
            }
        __builtin_amdgcn_s_setprio(0);

        // B-frag under remap: slot q*8+e holds V[key = 32kc+16(e>>2)+4q+(e&3)]
        // [d = nt*16+n]; two b64 reads concatenated.
        short8 vf[4][2];
#pragma unroll
        for (int nt = 0; nt < 4; ++nt) {
            const int rb = (nt * 16 + n) * 64;
#pragma unroll
            for (int kc = 0; kc < 2; ++kc) {
                const short4v g0 = *(const short4v*)&Vsm[cur][rb + vswz[kc][0]];
                const short4v g1 = *(const short4v*)&Vsm[cur][rb + vswz[kc][1]];
                vf[nt][kc] = __builtin_shufflevector(g0, g1, 0, 1, 2, 3, 4, 5, 6, 7);
            }
        }

#pragma unroll
        for (int mt = 0; mt < 4; ++mt) {
            // tile max for q = mt*16+n (my 16 keys, then across quads)
            float lm = s[mt][0][0];
#pragma unroll
            for (int ct = 0; ct < 4; ++ct)
#pragma unroll
                for (int r = 0; r < 4; ++r)
                    lm = fmaxf(lm, s[mt][ct][r]);
            lm = fmaxf(lm, __shfl_xor(lm, 16, 64));
            lm = fmaxf(lm, __shfl_xor(lm, 32, 64));

            const bool ev = lm > mrow[mt] + 8.0f;   // defer-max threshold
            if (__any(ev)) {
                const float mnew  = ev ? lm : mrow[mt];
                const float alpha = fexp2(mrow[mt] - mnew);  // 1.0 when !ev
                mrow[mt] = mnew;
                lrow[mt] *= alpha;
                const int ai = __float_as_int(alpha);
                float av[4];
#pragma unroll
                for (int r = 0; r < 4; ++r)
                    av[r] = __int_as_float(
                        __builtin_amdgcn_ds_bpermute(4 * (quad * 4 + r), ai));
#pragma unroll
                for (int nt = 0; nt < 4; ++nt)
#pragma unroll
                    for (int r = 0; r < 4; ++r) O[mt][nt][r] *= av[r];
            }

            // P = 2^(s - m); l as local partial (reduced once at the end)
            float pv[4][4];
            float lsum = 0.f;
#pragma unroll
            for (int ct = 0; ct < 4; ++ct)
#pragma unroll
                for (int r = 0; r < 4; ++r) {
                    const float p = fexp2(s[mt][ct][r] - mrow[mt]);
                    pv[ct][r] = p;
                    lsum += p;
                }
            lrow[mt] += lsum;

            // PV A-frag is PURELY LOCAL under the remap:
            // element e of pk[kc] = pv[2kc + (e>>2)][e&3]; cvt_pk = 1 instr.
            union { unsigned u[4]; short8 s8; } pk[2];
#pragma unroll
            for (int kc = 0; kc < 2; ++kc) {
                pk[kc].u[0] = cvtpk_bf16(pv[2 * kc][0],     pv[2 * kc][1]);
                pk[kc].u[1] = cvtpk_bf16(pv[2 * kc][2],     pv[2 * kc][3]);
                pk[kc].u[2] = cvtpk_bf16(pv[2 * kc + 1][0], pv[2 * kc + 1][1]);
                pk[kc].u[3] = cvtpk_bf16(pv[2 * kc + 1][2], pv[2 * kc + 1][3]);
            }

            __builtin_amdgcn_s_setprio(1);
#pragma unroll
            for (int nt = 0; nt < 4; ++nt) {
                O[mt][nt] = __builtin_amdgcn_mfma_f32_16x16x32_bf16(pk[0].s8, vf[nt][0], O[mt][nt], 0, 0, 0);
                O[mt][nt] = __builtin_amdgcn_mfma_f32_16x16x32_bf16(pk[1].s8, vf[nt][1], O[mt][nt], 0, 0, 0);
            }
            __builtin_amdgcn_s_setprio(0);
        }
    }

#pragma unroll
    for (int mt = 0; mt < 4; ++mt) {
        float ls = lrow[mt];
        ls += __shfl_xor(ls, 16, 64);
        ls += __shfl_xor(ls, 32, 64);
        const float linv = 1.f / ls;            // at lane: q = mt*16 + n
        const int  li = __float_as_int(linv);
        float lv[4];
#pragma unroll
        for (int r = 0; r < 4; ++r)
            lv[r] = __int_as_float(
                __builtin_amdgcn_ds_bpermute(4 * (quad * 4 + r), li));
#pragma unroll
        for (int nt = 0; nt < 4; ++nt)
#pragma unroll
            for (int r = 0; r < 4; ++r) {
                const int q = qbase + mt * 16 + quad * 4 + r;
                Yh[((size_t)(b * S_DIM + q) << 10) + h * DH + nt * 16 + n] =
                    f2bf(O[mt][nt][r] * lv[r]);
            }
    }
}

// ---------------------------------------------------------------------------
extern "C" void kernel_launch(void* const* d_in, const int* in_sizes, int n_in,
                              void* d_out, int out_size, void* d_ws, size_t ws_size,
                              hipStream_t stream)
{
    const float* x  = (const float*)d_in[0];
    const float* wq = (const float*)d_in[1];
    const float* wk = (const float*)d_in[2];
    const float* wv = (const float*)d_in[3];
    const float* wo = (const float*)d_in[4];
    const float* bo = (const float*)d_in[5];
    float* out = (float*)d_out;

    const size_t MD = (size_t)M_DIM * D_DIM;      // 4M elements
    const size_t WD = (size_t)D_DIM * D_DIM;      // 1M elements
    ushort* xh  = (ushort*)d_ws;      // 8 MB  [M,K] bf16
    ushort* Wh  = xh + MD;            // 6 MB  [3072,1024] bf16 (wq|wk|wv)
    ushort* Woh = Wh + 3 * WD;        // 2 MB  [1024,1024] bf16
    ushort* Qh  = Woh + WD;           // 8 MB  [B,H,S,Dh] bf16 (pre-scaled)
    ushort* Kh  = Qh + MD;            // 8 MB  [B,H,S,Dh] bf16
    ushort* Vt  = Kh + MD;            // 8 MB  [B,H,Dh,S] bf16
    ushort* Yh  = Vt + MD;            // 8 MB  [M,D] bf16
    if (ws_size < 48u * 1024u * 1024u) return;

    dim3 blk(256);
    cast_all<<<dim3(8192), blk, 0, stream>>>(x, wq, wk, wv, wo, xh);

    gemm_bf16<<<dim3(24, 32), blk, 0, stream>>>(xh, Wh, Qh, Kh, Vt, nullptr, nullptr, 0);
    attn_mfma<<<dim3(512), dim3(128), 0, stream>>>(Qh, Kh, Vt, Yh);
    gemm_bf16<<<dim3(8, 32), blk, 0, stream>>>(Yh, Woh, nullptr, nullptr, nullptr, out, bo, 1);
}

// Round 10
// 217.246 us; speedup vs baseline: 1.0556x; 1.0556x over previous
//
#include <hip/hip_runtime.h>
#include <math.h>

#define B_DIM 2
#define S_DIM 2048
#define D_DIM 1024
#define H_NUM 16
#define DH    64
#define M_DIM (B_DIM * S_DIM) /* 4096 */

typedef __attribute__((ext_vector_type(8))) short short8;
typedef __attribute__((ext_vector_type(4))) short short4v;
typedef __attribute__((ext_vector_type(4))) float float4v;
typedef __attribute__((ext_vector_type(4))) unsigned short ushort4v;
typedef unsigned short ushort;

static __device__ __forceinline__ ushort f2bf(float f) {
    unsigned u = __float_as_uint(f);
    u += 0x7fffu + ((u >> 16) & 1u);
    return (ushort)(u >> 16);
}

static __device__ __forceinline__ float fexp2(float x) {
#if __has_builtin(__builtin_amdgcn_exp2f)
    return __builtin_amdgcn_exp2f(x);
#else
    return exp2f(x);
#endif
}

// 2 f32 -> 2 bf16 in one u32, lo half = first arg (proven: rounds 3/4
// bit-identical).
static __device__ __forceinline__ unsigned cvtpk_bf16(float lo, float hi) {
    unsigned r;
    asm("v_cvt_pk_bf16_f32 %0, %1, %2" : "=v"(r) : "v"(lo), "v"(hi));
    return r;
}

static __device__ __forceinline__ void gload_lds16(const void* g, void* l) {
    __builtin_amdgcn_global_load_lds(
        (const __attribute__((address_space(1))) void*)g,
        (__attribute__((address_space(3))) void*)l, 16, 0, 0);
}

// ---------------------------------------------------------------------------
// Fused fp32 -> bf16 cast of ALL five tensors in one launch.
// dst layout (contiguous in ws): xh[4M] | wq[1M] | wk[1M] | wv[1M] | wo[1M]
// ---------------------------------------------------------------------------
__global__ __launch_bounds__(256)
void cast_all(const float* __restrict__ x,  const float* __restrict__ wq,
              const float* __restrict__ wk, const float* __restrict__ wv,
              const float* __restrict__ wo, ushort* __restrict__ dst)
{
    const int i = blockIdx.x * 256 + threadIdx.x;   // 0 .. 2M-1 (float4 units)
    const float4* s;
    int off;
    if      (i < 1048576) { s = (const float4*)x;  off = 0;       }
    else if (i < 1310720) { s = (const float4*)wq; off = 1048576; }
    else if (i < 1572864) { s = (const float4*)wk; off = 1310720; }
    else if (i < 1835008) { s = (const float4*)wv; off = 1572864; }
    else                  { s = (const float4*)wo; off = 1835008; }
    const float4 v = s[i - off];
    ushort4v o;
    o[0] = f2bf(v.x); o[1] = f2bf(v.y); o[2] = f2bf(v.z); o[3] = f2bf(v.w);
    ((ushort4v*)dst)[i] = o;
}

// ---------------------------------------------------------------------------
// bf16 MFMA GEMM, m97 structure: 128x128 tile, BK=32, global_load_lds w=16,
// 4 waves in 2x2, each wave 64x64 via 4x4 grid of 16x16x32 MFMAs.
// A:[M=4096, K=1024] bf16 row-major. B:[N=3072, K=1024] bf16 row-major.
// Fused QKV: n>>10 selects dst: 0->Qh [B,H,S,Dh] (PRE-SCALED by
// 0.125*log2e for base-2 online softmax), 1->Kh [B,H,S,Dh],
// 2->Vt [B,H,Dh,S]; all bf16.
// ---------------------------------------------------------------------------
__global__ __launch_bounds__(256)
void gemm_bf16(const ushort* __restrict__ A, const ushort* __restrict__ B,
               ushort* __restrict__ Qh, ushort* __restrict__ Kh,
               ushort* __restrict__ Vt)
{
    __shared__ ushort Asm[128 * 32];   // [row][k], 64B rows, lane-order (no pad!)
    __shared__ ushort Bsm[128 * 32];

    const int K  = 1024;
    const int n0 = blockIdx.x * 128;
    const int m0 = blockIdx.y * 128;
    const int t    = threadIdx.x;
    const int w    = t >> 6;
    const int lane = t & 63;
    const int n    = lane & 15;
    const int quad = lane >> 4;
    const int wm = w >> 1, wn = w & 1;

    const int srow = w * 32 + (lane >> 2);
    const int skel = (lane & 3) * 8;

    float4v acc[4][4];
#pragma unroll
    for (int mt = 0; mt < 4; ++mt)
#pragma unroll
        for (int nt = 0; nt < 4; ++nt) acc[mt][nt] = (float4v){0.f, 0.f, 0.f, 0.f};

    for (int kt = 0; kt < K; kt += 32) {
#pragma unroll
        for (int i = 0; i < 2; ++i) {
            gload_lds16(&A[(size_t)(m0 + srow + i * 16) * K + kt + skel],
                        &Asm[(w * 2 + i) * 512]);
            gload_lds16(&B[(size_t)(n0 + srow + i * 16) * K + kt + skel],
                        &Bsm[(w * 2 + i) * 512]);
        }
        __syncthreads();

        short8 af[4], bfr[4];
#pragma unroll
        for (int mt = 0; mt < 4; ++mt)
            af[mt] = *(const short8*)&Asm[(wm * 64 + mt * 16 + n) * 32 + quad * 8];
#pragma unroll
        for (int nt = 0; nt < 4; ++nt)
            bfr[nt] = *(const short8*)&Bsm[(wn * 64 + nt * 16 + n) * 32 + quad * 8];

#pragma unroll
        for (int mt = 0; mt < 4; ++mt)
#pragma unroll
            for (int nt = 0; nt < 4; ++nt)
                acc[mt][nt] = __builtin_amdgcn_mfma_f32_16x16x32_bf16(
                    af[mt], bfr[nt], acc[mt][nt], 0, 0, 0);
        __syncthreads();
    }

    const int wid = n0 >> 10;           // 0=Q 1=K 2=V (constant per block)
    ushort* dstQK = (wid == 0) ? Qh : Kh;
    const float qs = (wid == 0) ? 0.1803368801f : 1.0f;  // 0.125*log2(e)
#pragma unroll
    for (int mt = 0; mt < 4; ++mt) {
        const int m = m0 + wm * 64 + mt * 16 + quad * 4;   // +r
        const int b = m >> 11, s = m & (S_DIM - 1);
#pragma unroll
        for (int nt = 0; nt < 4; ++nt) {
            const int ng = (n0 & 1023) + wn * 64 + nt * 16 + n;
            const int h = ng >> 6, d = ng & 63;
            const int bh = b * H_NUM + h;
            if (wid < 2) {
#pragma unroll
                for (int r = 0; r < 4; ++r)
                    dstQK[(((size_t)bh * S_DIM + s + r) << 6) + d] =
                        f2bf(acc[mt][nt][r] * qs);
            } else {
                ushort4v p;
#pragma unroll
                for (int r = 0; r < 4; ++r) p[r] = f2bf(acc[mt][nt][r]);
                *(ushort4v*)&Vt[(((size_t)bh * DH + d) << 11) + s] = p;
            }
        }
    }
}

// ---------------------------------------------------------------------------
// Out-projection GEMM, 128x64 tile (BM=128, BN=64). Rationale: the 128x128
// version launched (8,32)=256 blocks = 1 block/CU -- the occupancy outlier.
// 128x64 -> grid (16,32)=512 blocks = 2 blocks/CU, same total MFMA work.
// 4 waves in 2x2, each wave 64x32 via 4x2 grid of 16x16x32 MFMAs.
// A=Yh [4096,1024] bf16, B=Woh [1024,1024] bf16 (row-major, y = x@W^T).
// fp32 out[m*1024+n] = acc + bias[n].
// ---------------------------------------------------------------------------
__global__ __launch_bounds__(256)
void gemm_out(const ushort* __restrict__ A, const ushort* __restrict__ B,
              float* __restrict__ Of, const float* __restrict__ bias)
{
    __shared__ ushort Asm[128 * 32];
    __shared__ ushort Bsm[64 * 32];

    const int K  = 1024;
    const int n0 = blockIdx.x * 64;
    const int m0 = blockIdx.y * 128;
    const int t    = threadIdx.x;
    const int w    = t >> 6;
    const int lane = t & 63;
    const int n    = lane & 15;
    const int quad = lane >> 4;
    const int wm = w >> 1, wn = w & 1;

    const int srow  = w * 32 + (lane >> 2);   // A staging rows (2x16 per wave)
    const int srowB = w * 16 + (lane >> 2);   // B staging rows (1x16 per wave)
    const int skel  = (lane & 3) * 8;

    float4v acc[4][2];
#pragma unroll
    for (int mt = 0; mt < 4; ++mt)
#pragma unroll
        for (int nt = 0; nt < 2; ++nt) acc[mt][nt] = (float4v){0.f, 0.f, 0.f, 0.f};

    for (int kt = 0; kt < K; kt += 32) {
#pragma unroll
        for (int i = 0; i < 2; ++i)
            gload_lds16(&A[(size_t)(m0 + srow + i * 16) * K + kt + skel],
                        &Asm[(w * 2 + i) * 512]);
        gload_lds16(&B[(size_t)(n0 + srowB) * K + kt + skel], &Bsm[w * 512]);
        __syncthreads();

        short8 af[4], bfr[2];
#pragma unroll
        for (int mt = 0; mt < 4; ++mt)
            af[mt] = *(const short8*)&Asm[(wm * 64 + mt * 16 + n) * 32 + quad * 8];
#pragma unroll
        for (int nt = 0; nt < 2; ++nt)
            bfr[nt] = *(const short8*)&Bsm[(wn * 32 + nt * 16 + n) * 32 + quad * 8];

#pragma unroll
        for (int mt = 0; mt < 4; ++mt)
#pragma unroll
            for (int nt = 0; nt < 2; ++nt)
                acc[mt][nt] = __builtin_amdgcn_mfma_f32_16x16x32_bf16(
                    af[mt], bfr[nt], acc[mt][nt], 0, 0, 0);
        __syncthreads();
    }

#pragma unroll
    for (int mt = 0; mt < 4; ++mt) {
        const int m = m0 + wm * 64 + mt * 16 + quad * 4;
#pragma unroll
        for (int nt = 0; nt < 2; ++nt) {
            const int ng = n0 + wn * 32 + nt * 16 + n;
            const float bv = bias[ng];
#pragma unroll
            for (int r = 0; r < 4; ++r)
                Of[(size_t)(m + r) * D_DIM + ng] = acc[mt][nt][r] + bv;
        }
    }
}

// ---------------------------------------------------------------------------
// MFMA flash attention: round-7 geometry EXACT (32 q-rows/wave, 4-wave
// blocks, grid 512 -> 8 waves/CU; R6/R9 bounded this as the optimum of the
// structure), with two VALU cuts at fixed geometry:
//  - l-sum via MFMA against an all-ones B-fragment: l accumulates in O's
//    (quad,r) layout directly. Deletes 32 lsum adds/kb + the final
//    shfl/bpermute l-reduction; costs 4 MFMA/kb on the 19%-busy MFMA pipe.
//  - tree-shaped tile-max (depth 4 vs serial-16; max3-fusable).
// Swapped QK^T, fully LOCAL P->PV handoff via the k-slot->key remap
// slot q*8+e <-> key 32kc+16(e>>2)+4q+(e&3) (A and B use the same map).
// Defer-max (THR=8, base-2); Q pre-scaled by 0.125*log2e; cvt_pk packing.
// ---------------------------------------------------------------------------
__global__ __launch_bounds__(256)
void attn_mfma(const ushort* __restrict__ Qh, const ushort* __restrict__ Kh,
               const ushort* __restrict__ Vt, ushort* __restrict__ Yh)
{
    __shared__ ushort Ksm[2][64 * 64];   // [buf][key 64][d 64] granule-swizzled
    __shared__ ushort Vsm[2][64 * 64];   // [buf][d 64][key 64] granule-swizzled

    const int w    = threadIdx.x >> 6;
    const int lane = threadIdx.x & 63;
    const int n    = lane & 15;
    const int quad = lane >> 4;

    const int wave_id = blockIdx.x * 4 + w;
    const int bh    = wave_id >> 6;          // all 4 waves of a block: same bh
    const int qbase = (wave_id & 63) * 32;
    const int b     = bh >> 4;
    const int h     = bh & (H_NUM - 1);

    const ushort* Qb = Qh + (((size_t)bh * S_DIM) << 6);
    const ushort* Kb = Kh + (((size_t)bh * S_DIM) << 6);
    const ushort* Vb = Vt + (((size_t)bh * DH) << 11);

    // staging: lane l covers row sub-index l>>3, 16B granule (l&7), source
    // granule pre-swizzled (gload_lds dst must stay linear).
    const int l8 = lane >> 3;
    const int sg = (lane & 7) ^ l8;

    short8 qa[2][2];   // B-frag: lane holds Q[q = mt*16+n][d = kc*32+quad*8 ..]
#pragma unroll
    for (int mt = 0; mt < 2; ++mt)
#pragma unroll
        for (int kc = 0; kc < 2; ++kc)
            qa[mt][kc] = *(const short8*)&Qb[((size_t)(qbase + mt * 16 + n) << 6) + kc * 32 + quad * 8];

    // all-ones bf16 B-fragment for the l-sum MFMA
    short8 ones;
#pragma unroll
    for (int e = 0; e < 8; ++e) ones[e] = (short)0x3F80;

    float4v O[2][4];   // O[mt][nt][r]: q = mt*16+quad*4+r, d = nt*16+n
    float4v Ol[2];     // Ol[mt][r]  : l for q = mt*16+quad*4+r (same at all n)
    float   mrow[2];   // per-lane: q = mt*16 + n (uniform over quads)
#pragma unroll
    for (int mt = 0; mt < 2; ++mt) {
#pragma unroll
        for (int nt = 0; nt < 4; ++nt) O[mt][nt] = (float4v){0.f, 0.f, 0.f, 0.f};
        Ol[mt] = (float4v){0.f, 0.f, 0.f, 0.f};
        mrow[mt] = -1e30f;
    }

    // K fragment-read offsets (ushort units): logical granule g at row rr is
    // stored at physical g ^ (rr&7); rr&7 == n&7 for rr = ct*16 + n.
    const int fswz[2] = { ((0 * 4 + quad) ^ (n & 7)) * 8,
                          ((1 * 4 + quad) ^ (n & 7)) * 8 };
    // V b64 read offsets for the slot-key remap: for kc, cc: logical granule
    // 4kc + 2cc + (quad>>1), half (quad&1); physical = logical ^ (n&7).
    const int h4 = (quad & 1) * 4;
    const int q2 = quad >> 1;
    int vswz[2][2];
#pragma unroll
    for (int kc = 0; kc < 2; ++kc)
#pragma unroll
        for (int cc = 0; cc < 2; ++cc)
            vswz[kc][cc] = (((4 * kc + 2 * cc + q2) ^ (n & 7)) << 3) + h4;

    // prologue: stage tile 0 into buffer 0
#pragma unroll
    for (int i = 0; i < 2; ++i) {
        gload_lds16(&Kb[(size_t)(w * 16 + i * 8 + l8) * 64 + sg * 8],
                    &Ksm[0][(w * 16 + i * 8) * 64]);
        gload_lds16(&Vb[(size_t)(w * 16 + i * 8 + l8) * 2048 + sg * 8],
                    &Vsm[0][(w * 16 + i * 8) * 64]);
    }

    for (int kb = 0; kb < S_DIM / 64; ++kb) {
        __syncthreads();   // stage(kb) complete; buf cur^1 free for overwrite
        const int cur = kb & 1;
        if (kb + 1 < S_DIM / 64) {
            const int key1 = (kb + 1) * 64;
            const int nxt  = cur ^ 1;
#pragma unroll
            for (int i = 0; i < 2; ++i) {
                gload_lds16(&Kb[(size_t)(key1 + w * 16 + i * 8 + l8) * 64 + sg * 8],
                            &Ksm[nxt][(w * 16 + i * 8) * 64]);
                gload_lds16(&Vb[(size_t)(w * 16 + i * 8 + l8) * 2048 + key1 + sg * 8],
                            &Vsm[nxt][(w * 16 + i * 8) * 64]);
            }
        }

        // A-frag: lane holds K[key = ct*16+n][d = kc*32+quad*8 ..]
        short8 kf[4][2];
#pragma unroll
        for (int ct = 0; ct < 4; ++ct)
#pragma unroll
            for (int kc = 0; kc < 2; ++kc)
                kf[ct][kc] = *(const short8*)&Ksm[cur][(ct * 16 + n) * 64 + fswz[kc]];

        // S^T[key][q]: s[mt][ct][r] = S[q = mt*16+n][key = ct*16+quad*4+r]
        float4v s[2][4];
        __builtin_amdgcn_s_setprio(1);
#pragma unroll
        for (int mt = 0; mt < 2; ++mt)
#pragma unroll
            for (int ct = 0; ct < 4; ++ct) {
                float4v a = (float4v){0.f, 0.f, 0.f, 0.f};
                a = __builtin_amdgcn_mfma_f32_16x16x32_bf16(kf[ct][0], qa[mt][0], a, 0, 0, 0);
                a = __builtin_amdgcn_mfma_f32_16x16x32_bf16(kf[ct][1], qa[mt][1], a, 0, 0, 0);
                s[mt][ct] = a;
            }
        __builtin_amdgcn_s_setprio(0);

        // B-frag under remap: slot q*8+e holds V[key = 32kc+16(e>>2)+4q+(e&3)]
        // [d = nt*16+n]; two b64 reads concatenated.
        short8 vf[4][2];
#pragma unroll
        for (int nt = 0; nt < 4; ++nt) {
            const int rb = (nt * 16 + n) * 64;
#pragma unroll
            for (int kc = 0; kc < 2; ++kc) {
                const short4v g0 = *(const short4v*)&Vsm[cur][rb + vswz[kc][0]];
                const short4v g1 = *(const short4v*)&Vsm[cur][rb + vswz[kc][1]];
                vf[nt][kc] = __builtin_shufflevector(g0, g1, 0, 1, 2, 3, 4, 5, 6, 7);
            }
        }

#pragma unroll
        for (int mt = 0; mt < 2; ++mt) {
            // tile max for q = mt*16+n: tree (depth 4, max3-fusable), then quads
            float cmx[4];
#pragma unroll
            for (int ct = 0; ct < 4; ++ct)
                cmx[ct] = fmaxf(fmaxf(s[mt][ct][0], s[mt][ct][1]),
                                fmaxf(s[mt][ct][2], s[mt][ct][3]));
            float lm = fmaxf(fmaxf(cmx[0], cmx[1]), fmaxf(cmx[2], cmx[3]));
            lm = fmaxf(lm, __shfl_xor(lm, 16, 64));
            lm = fmaxf(lm, __shfl_xor(lm, 32, 64));

            const bool ev = lm > mrow[mt] + 8.0f;   // defer-max threshold
            if (__any(ev)) {
                const float mnew  = ev ? lm : mrow[mt];
                const float alpha = fexp2(mrow[mt] - mnew);  // 1.0 when !ev
                mrow[mt] = mnew;
                const int ai = __float_as_int(alpha);
                float av[4];
#pragma unroll
                for (int r = 0; r < 4; ++r)
                    av[r] = __int_as_float(
                        __builtin_amdgcn_ds_bpermute(4 * (quad * 4 + r), ai));
#pragma unroll
                for (int nt = 0; nt < 4; ++nt)
#pragma unroll
                    for (int r = 0; r < 4; ++r) O[mt][nt][r] *= av[r];
#pragma unroll
                for (int r = 0; r < 4; ++r) Ol[mt][r] *= av[r];
            }

            // P = 2^(s - m)
            float pv[4][4];
#pragma unroll
            for (int ct = 0; ct < 4; ++ct)
#pragma unroll
                for (int r = 0; r < 4; ++r)
                    pv[ct][r] = fexp2(s[mt][ct][r] - mrow[mt]);

            // PV A-frag is PURELY LOCAL under the remap:
            // element e of pk[kc] = pv[2kc + (e>>2)][e&3]; cvt_pk = 1 instr.
            union { unsigned u[4]; short8 s8; } pk[2];
#pragma unroll
            for (int kc = 0; kc < 2; ++kc) {
                pk[kc].u[0] = cvtpk_bf16(pv[2 * kc][0],     pv[2 * kc][1]);
                pk[kc].u[1] = cvtpk_bf16(pv[2 * kc][2],     pv[2 * kc][3]);
                pk[kc].u[2] = cvtpk_bf16(pv[2 * kc + 1][0], pv[2 * kc + 1][1]);
                pk[kc].u[3] = cvtpk_bf16(pv[2 * kc + 1][2], pv[2 * kc + 1][3]);
            }

            __builtin_amdgcn_s_setprio(1);
#pragma unroll
            for (int nt = 0; nt < 4; ++nt) {
                O[mt][nt] = __builtin_amdgcn_mfma_f32_16x16x32_bf16(pk[0].s8, vf[nt][0], O[mt][nt], 0, 0, 0);
                O[mt][nt] = __builtin_amdgcn_mfma_f32_16x16x32_bf16(pk[1].s8, vf[nt][1], O[mt][nt], 0, 0, 0);
            }
            // l-sum on the MFMA pipe: D[q][*] = sum_k P[q][k] (B = ones)
            Ol[mt] = __builtin_amdgcn_mfma_f32_16x16x32_bf16(pk[0].s8, ones, Ol[mt], 0, 0, 0);
            Ol[mt] = __builtin_amdgcn_mfma_f32_16x16x32_bf16(pk[1].s8, ones, Ol[mt], 0, 0, 0);
            __builtin_amdgcn_s_setprio(0);
        }
    }

#pragma unroll
    for (int mt = 0; mt < 2; ++mt) {
#pragma unroll
        for (int r = 0; r < 4; ++r) {
            const float linv = 1.f / Ol[mt][r];   // q = mt*16+quad*4+r
            const int q = qbase + mt * 16 + quad * 4 + r;
#pragma unroll
            for (int nt = 0; nt < 4; ++nt)
                Yh[((size_t)(b * S_DIM + q) << 10) + h * DH + nt * 16 + n] =
                    f2bf(O[mt][nt][r] * linv);
        }
    }
}

// ---------------------------------------------------------------------------
extern "C" void kernel_launch(void* const* d_in, const int* in_sizes, int n_in,
                              void* d_out, int out_size, void* d_ws, size_t ws_size,
                              hipStream_t stream)
{
    const float* x  = (const float*)d_in[0];
    const float* wq = (const float*)d_in[1];
    const float* wk = (const float*)d_in[2];
    const float* wv = (const float*)d_in[3];
    const float* wo = (const float*)d_in[4];
    const float* bo = (const float*)d_in[5];
    float* out = (float*)d_out;

    const size_t MD = (size_t)M_DIM * D_DIM;      // 4M elements
    const size_t WD = (size_t)D_DIM * D_DIM;      // 1M elements
    ushort* xh  = (ushort*)d_ws;      // 8 MB  [M,K] bf16
    ushort* Wh  = xh + MD;            // 6 MB  [3072,1024] bf16 (wq|wk|wv)
    ushort* Woh = Wh + 3 * WD;        // 2 MB  [1024,1024] bf16
    ushort* Qh  = Woh + WD;           // 8 MB  [B,H,S,Dh] bf16 (pre-scaled)
    ushort* Kh  = Qh + MD;            // 8 MB  [B,H,S,Dh] bf16
    ushort* Vt  = Kh + MD;            // 8 MB  [B,H,Dh,S] bf16
    ushort* Yh  = Vt + MD;            // 8 MB  [M,D] bf16
    if (ws_size < 48u * 1024u * 1024u) return;

    dim3 blk(256);
    cast_all<<<dim3(8192), blk, 0, stream>>>(x, wq, wk, wv, wo, xh);

    gemm_bf16<<<dim3(24, 32), blk, 0, stream>>>(xh, Wh, Qh, Kh, Vt);
    attn_mfma<<<dim3(512), blk, 0, stream>>>(Qh, Kh, Vt, Yh);
    gemm_out<<<dim3(16, 32), blk, 0, stream>>>(Yh, Woh, out, bo);
}

// Round 11
// 207.813 us; speedup vs baseline: 1.1035x; 1.0454x over previous
//
#include <hip/hip_runtime.h>
#include <math.h>

#define B_DIM 2
#define S_DIM 2048
#define D_DIM 1024
#define H_NUM 16
#define DH    64
#define M_DIM (B_DIM * S_DIM) /* 4096 */

typedef __attribute__((ext_vector_type(8))) short short8;
typedef __attribute__((ext_vector_type(4))) short short4v;
typedef __attribute__((ext_vector_type(4))) float float4v;
typedef __attribute__((ext_vector_type(4))) unsigned short ushort4v;
typedef unsigned short ushort;

static __device__ __forceinline__ ushort f2bf(float f) {
    unsigned u = __float_as_uint(f);
    u += 0x7fffu + ((u >> 16) & 1u);
    return (ushort)(u >> 16);
}

static __device__ __forceinline__ float fexp2(float x) {
#if __has_builtin(__builtin_amdgcn_exp2f)
    return __builtin_amdgcn_exp2f(x);
#else
    return exp2f(x);
#endif
}

// 2 f32 -> 2 bf16 in one u32, lo half = first arg (proven: rounds 3/4
// bit-identical).
static __device__ __forceinline__ unsigned cvtpk_bf16(float lo, float hi) {
    unsigned r;
    asm("v_cvt_pk_bf16_f32 %0, %1, %2" : "=v"(r) : "v"(lo), "v"(hi));
    return r;
}

static __device__ __forceinline__ void gload_lds16(const void* g, void* l) {
    __builtin_amdgcn_global_load_lds(
        (const __attribute__((address_space(1))) void*)g,
        (__attribute__((address_space(3))) void*)l, 16, 0, 0);
}

// ---------------------------------------------------------------------------
// Fused fp32 -> bf16 cast of ALL five tensors in one launch.
// dst layout (contiguous in ws): xh[4M] | wq[1M] | wk[1M] | wv[1M] | wo[1M]
// ---------------------------------------------------------------------------
__global__ __launch_bounds__(256)
void cast_all(const float* __restrict__ x,  const float* __restrict__ wq,
              const float* __restrict__ wk, const float* __restrict__ wv,
              const float* __restrict__ wo, ushort* __restrict__ dst)
{
    const int i = blockIdx.x * 256 + threadIdx.x;   // 0 .. 2M-1 (float4 units)
    const float4* s;
    int off;
    if      (i < 1048576) { s = (const float4*)x;  off = 0;       }
    else if (i < 1310720) { s = (const float4*)wq; off = 1048576; }
    else if (i < 1572864) { s = (const float4*)wk; off = 1310720; }
    else if (i < 1835008) { s = (const float4*)wv; off = 1572864; }
    else                  { s = (const float4*)wo; off = 1835008; }
    const float4 v = s[i - off];
    ushort4v o;
    o[0] = f2bf(v.x); o[1] = f2bf(v.y); o[2] = f2bf(v.z); o[3] = f2bf(v.w);
    ((ushort4v*)dst)[i] = o;
}

// ---------------------------------------------------------------------------
// QKV GEMM, BK=64 (halves the per-block barrier-drain count vs BK=32: the
// K-loop is only 1024 deep, so the vmcnt(0)+barrier stall per K-step was
// amortized 4x worse than the reference 4096-deep shape). 128-B LDS rows
// would 16-way conflict on fragment ds_reads; fixed with the attn kernel's
// verified granule-XOR pattern: pre-swizzled GLOBAL source granule + linear
// gload_lds dst + XOR'd read offsets. XCD-aware bijective swizzle (768=8*96)
// gives each XCD contiguous m-rows: A-panel L2-reused 24x consecutively.
// A:[4096,1024] bf16, B:[3072,1024] bf16 row-major.
// n>>10 selects dst: 0->Qh [B,H,S,Dh] (PRE-SCALED by 0.125*log2e),
// 1->Kh [B,H,S,Dh], 2->Vt [B,H,Dh,S]; all bf16.
// ---------------------------------------------------------------------------
__global__ __launch_bounds__(256)
void gemm_bf16(const ushort* __restrict__ A, const ushort* __restrict__ B,
               ushort* __restrict__ Qh, ushort* __restrict__ Kh,
               ushort* __restrict__ Vt)
{
    __shared__ ushort Asm[128 * 64];   // [row][k 64], granule-swizzled
    __shared__ ushort Bsm[128 * 64];

    const int K = 1024;
    const int lin = blockIdx.y * 24 + blockIdx.x;      // hardware linear id
    const int swz = (lin & 7) * 96 + (lin >> 3);       // bijective (768=8*96)
    const int n0 = (swz % 24) * 128;
    const int m0 = (swz / 24) * 128;
    const int t    = threadIdx.x;
    const int w    = t >> 6;
    const int lane = t & 63;
    const int n    = lane & 15;
    const int quad = lane >> 4;
    const int wm = w >> 1, wn = w & 1;

    // staging: lane covers row sub-index lane>>3, granule (lane&7);
    // source granule pre-swizzled by row&7 (gload_lds dst stays linear)
    const int l8 = lane >> 3;
    const int sg = (lane & 7) ^ l8;

    // fragment-read offsets: logical granule kk*4+quad at row rr stored at
    // physical (kk*4+quad)^(rr&7); rr&7 == n&7 for rr = base16*i + n.
    const int fswz[2] = { ((0 * 4 + quad) ^ (n & 7)) * 8,
                          ((1 * 4 + quad) ^ (n & 7)) * 8 };

    float4v acc[4][4];
#pragma unroll
    for (int mt = 0; mt < 4; ++mt)
#pragma unroll
        for (int nt = 0; nt < 4; ++nt) acc[mt][nt] = (float4v){0.f, 0.f, 0.f, 0.f};

    for (int kt = 0; kt < K; kt += 64) {
#pragma unroll
        for (int i = 0; i < 4; ++i) {
            gload_lds16(&A[(size_t)(m0 + w * 32 + i * 8 + l8) * K + kt + sg * 8],
                        &Asm[(w * 32 + i * 8) * 64]);
            gload_lds16(&B[(size_t)(n0 + w * 32 + i * 8 + l8) * K + kt + sg * 8],
                        &Bsm[(w * 32 + i * 8) * 64]);
        }
        __syncthreads();

        short8 af[4][2], bfr[4][2];
#pragma unroll
        for (int mt = 0; mt < 4; ++mt)
#pragma unroll
            for (int kk = 0; kk < 2; ++kk)
                af[mt][kk] = *(const short8*)&Asm[(wm * 64 + mt * 16 + n) * 64 + fswz[kk]];
#pragma unroll
        for (int nt = 0; nt < 4; ++nt)
#pragma unroll
            for (int kk = 0; kk < 2; ++kk)
                bfr[nt][kk] = *(const short8*)&Bsm[(wn * 64 + nt * 16 + n) * 64 + fswz[kk]];

#pragma unroll
        for (int mt = 0; mt < 4; ++mt)
#pragma unroll
            for (int nt = 0; nt < 4; ++nt) {
                acc[mt][nt] = __builtin_amdgcn_mfma_f32_16x16x32_bf16(
                    af[mt][0], bfr[nt][0], acc[mt][nt], 0, 0, 0);
                acc[mt][nt] = __builtin_amdgcn_mfma_f32_16x16x32_bf16(
                    af[mt][1], bfr[nt][1], acc[mt][nt], 0, 0, 0);
            }
        __syncthreads();
    }

    const int wid = n0 >> 10;           // 0=Q 1=K 2=V (constant per block)
    ushort* dstQK = (wid == 0) ? Qh : Kh;
    const float qs = (wid == 0) ? 0.1803368801f : 1.0f;  // 0.125*log2(e)
#pragma unroll
    for (int mt = 0; mt < 4; ++mt) {
        const int m = m0 + wm * 64 + mt * 16 + quad * 4;   // +r
        const int b = m >> 11, s = m & (S_DIM - 1);
#pragma unroll
        for (int nt = 0; nt < 4; ++nt) {
            const int ng = (n0 & 1023) + wn * 64 + nt * 16 + n;
            const int h = ng >> 6, d = ng & 63;
            const int bh = b * H_NUM + h;
            if (wid < 2) {
#pragma unroll
                for (int r = 0; r < 4; ++r)
                    dstQK[(((size_t)bh * S_DIM + s + r) << 6) + d] =
                        f2bf(acc[mt][nt][r] * qs);
            } else {
                ushort4v p;
#pragma unroll
                for (int r = 0; r < 4; ++r) p[r] = f2bf(acc[mt][nt][r]);
                *(ushort4v*)&Vt[(((size_t)bh * DH + d) << 11) + s] = p;
            }
        }
    }
}

// ---------------------------------------------------------------------------
// Out-projection GEMM, 128x64 tile, BK=64, same swizzled-staging pattern.
// Grid (16,32)=512 blocks = 2 blocks/CU; XCD swizzle bijective (512=8*64).
// A=Yh [4096,1024] bf16, B=Woh [1024,1024] bf16 (row-major, y = x@W^T).
// fp32 out[m*1024+n] = acc + bias[n].
// ---------------------------------------------------------------------------
__global__ __launch_bounds__(256)
void gemm_out(const ushort* __restrict__ A, const ushort* __restrict__ B,
              float* __restrict__ Of, const float* __restrict__ bias)
{
    __shared__ ushort Asm[128 * 64];
    __shared__ ushort Bsm[64 * 64];

    const int K = 1024;
    const int lin = blockIdx.y * 16 + blockIdx.x;
    const int swz = (lin & 7) * 64 + (lin >> 3);       // bijective (512=8*64)
    const int n0 = (swz % 16) * 64;
    const int m0 = (swz / 16) * 128;
    const int t    = threadIdx.x;
    const int w    = t >> 6;
    const int lane = t & 63;
    const int n    = lane & 15;
    const int quad = lane >> 4;
    const int wm = w >> 1, wn = w & 1;

    const int l8 = lane >> 3;
    const int sg = (lane & 7) ^ l8;
    const int fswz[2] = { ((0 * 4 + quad) ^ (n & 7)) * 8,
                          ((1 * 4 + quad) ^ (n & 7)) * 8 };

    float4v acc[4][2];
#pragma unroll
    for (int mt = 0; mt < 4; ++mt)
#pragma unroll
        for (int nt = 0; nt < 2; ++nt) acc[mt][nt] = (float4v){0.f, 0.f, 0.f, 0.f};

    for (int kt = 0; kt < K; kt += 64) {
#pragma unroll
        for (int i = 0; i < 4; ++i)
            gload_lds16(&A[(size_t)(m0 + w * 32 + i * 8 + l8) * K + kt + sg * 8],
                        &Asm[(w * 32 + i * 8) * 64]);
#pragma unroll
        for (int i = 0; i < 2; ++i)
            gload_lds16(&B[(size_t)(n0 + w * 16 + i * 8 + l8) * K + kt + sg * 8],
                        &Bsm[(w * 16 + i * 8) * 64]);
        __syncthreads();

        short8 af[4][2], bfr[2][2];
#pragma unroll
        for (int mt = 0; mt < 4; ++mt)
#pragma unroll
            for (int kk = 0; kk < 2; ++kk)
                af[mt][kk] = *(const short8*)&Asm[(wm * 64 + mt * 16 + n) * 64 + fswz[kk]];
#pragma unroll
        for (int nt = 0; nt < 2; ++nt)
#pragma unroll
            for (int kk = 0; kk < 2; ++kk)
                bfr[nt][kk] = *(const short8*)&Bsm[(wn * 32 + nt * 16 + n) * 64 + fswz[kk]];

#pragma unroll
        for (int mt = 0; mt < 4; ++mt)
#pragma unroll
            for (int nt = 0; nt < 2; ++nt) {
                acc[mt][nt] = __builtin_amdgcn_mfma_f32_16x16x32_bf16(
                    af[mt][0], bfr[nt][0], acc[mt][nt], 0, 0, 0);
                acc[mt][nt] = __builtin_amdgcn_mfma_f32_16x16x32_bf16(
                    af[mt][1], bfr[nt][1], acc[mt][nt], 0, 0, 0);
            }
        __syncthreads();
    }

#pragma unroll
    for (int mt = 0; mt < 4; ++mt) {
        const int m = m0 + wm * 64 + mt * 16 + quad * 4;
#pragma unroll
        for (int nt = 0; nt < 2; ++nt) {
            const int ng = n0 + wn * 32 + nt * 16 + n;
            const float bv = bias[ng];
#pragma unroll
            for (int r = 0; r < 4; ++r)
                Of[(size_t)(m + r) * D_DIM + ng] = acc[mt][nt][r] + bv;
        }
    }
}

// ---------------------------------------------------------------------------
// MFMA flash attention: EXACT round-7 kernel (measured best: 69.5 us).
// Round-10's MFMA l-sum + tree-max regressed (+5 us: the l-sum MFMAs sit on
// the wave critical path right after PV) -- reverted.
// 32 q-rows/wave, 4-wave blocks, grid 512. Swapped QK^T, fully LOCAL P->PV
// handoff via the k-slot->key remap slot q*8+e <-> key 32kc+16(e>>2)+4q+(e&3).
// Defer-max (THR=8, base-2); Q pre-scaled by 0.125*log2e; cvt_pk packing.
// ---------------------------------------------------------------------------
__global__ __launch_bounds__(256)
void attn_mfma(const ushort* __restrict__ Qh, const ushort* __restrict__ Kh,
               const ushort* __restrict__ Vt, ushort* __restrict__ Yh)
{
    __shared__ ushort Ksm[2][64 * 64];   // [buf][key 64][d 64] granule-swizzled
    __shared__ ushort Vsm[2][64 * 64];   // [buf][d 64][key 64] granule-swizzled

    const int w    = threadIdx.x >> 6;
    const int lane = threadIdx.x & 63;
    const int n    = lane & 15;
    const int quad = lane >> 4;

    const int wave_id = blockIdx.x * 4 + w;
    const int bh    = wave_id >> 6;          // all 4 waves of a block: same bh
    const int qbase = (wave_id & 63) * 32;
    const int b     = bh >> 4;
    const int h     = bh & (H_NUM - 1);

    const ushort* Qb = Qh + (((size_t)bh * S_DIM) << 6);
    const ushort* Kb = Kh + (((size_t)bh * S_DIM) << 6);
    const ushort* Vb = Vt + (((size_t)bh * DH) << 11);

    const int l8 = lane >> 3;
    const int sg = (lane & 7) ^ l8;

    short8 qa[2][2];   // B-frag: lane holds Q[q = mt*16+n][d = kc*32+quad*8 ..]
#pragma unroll
    for (int mt = 0; mt < 2; ++mt)
#pragma unroll
        for (int kc = 0; kc < 2; ++kc)
            qa[mt][kc] = *(const short8*)&Qb[((size_t)(qbase + mt * 16 + n) << 6) + kc * 32 + quad * 8];

    float4v O[2][4];           // O[mt][nt][r]: q = mt*16+quad*4+r, d = nt*16+n
    float   mrow[2], lrow[2];  // per-lane: q = mt*16 + n (uniform over quads)
#pragma unroll
    for (int mt = 0; mt < 2; ++mt) {
#pragma unroll
        for (int nt = 0; nt < 4; ++nt) O[mt][nt] = (float4v){0.f, 0.f, 0.f, 0.f};
        mrow[mt] = -1e30f; lrow[mt] = 0.f;
    }

    const int fswz[2] = { ((0 * 4 + quad) ^ (n & 7)) * 8,
                          ((1 * 4 + quad) ^ (n & 7)) * 8 };
    const int h4 = (quad & 1) * 4;
    const int q2 = quad >> 1;
    int vswz[2][2];
#pragma unroll
    for (int kc = 0; kc < 2; ++kc)
#pragma unroll
        for (int cc = 0; cc < 2; ++cc)
            vswz[kc][cc] = (((4 * kc + 2 * cc + q2) ^ (n & 7)) << 3) + h4;

    // prologue: stage tile 0 into buffer 0
#pragma unroll
    for (int i = 0; i < 2; ++i) {
        gload_lds16(&Kb[(size_t)(w * 16 + i * 8 + l8) * 64 + sg * 8],
                    &Ksm[0][(w * 16 + i * 8) * 64]);
        gload_lds16(&Vb[(size_t)(w * 16 + i * 8 + l8) * 2048 + sg * 8],
                    &Vsm[0][(w * 16 + i * 8) * 64]);
    }

    for (int kb = 0; kb < S_DIM / 64; ++kb) {
        __syncthreads();   // stage(kb) complete; buf cur^1 free for overwrite
        const int cur = kb & 1;
        if (kb + 1 < S_DIM / 64) {
            const int key1 = (kb + 1) * 64;
            const int nxt  = cur ^ 1;
#pragma unroll
            for (int i = 0; i < 2; ++i) {
                gload_lds16(&Kb[(size_t)(key1 + w * 16 + i * 8 + l8) * 64 + sg * 8],
                            &Ksm[nxt][(w * 16 + i * 8) * 64]);
                gload_lds16(&Vb[(size_t)(w * 16 + i * 8 + l8) * 2048 + key1 + sg * 8],
                            &Vsm[nxt][(w * 16 + i * 8) * 64]);
            }
        }

        // A-frag: lane holds K[key = ct*16+n][d = kc*32+quad*8 ..]
        short8 kf[4][2];
#pragma unroll
        for (int ct = 0; ct < 4; ++ct)
#pragma unroll
            for (int kc = 0; kc < 2; ++kc)
                kf[ct][kc] = *(const short8*)&Ksm[cur][(ct * 16 + n) * 64 + fswz[kc]];

        // S^T[key][q]: s[mt][ct][r] = S[q = mt*16+n][key = ct*16+quad*4+r]
        float4v s[2][4];
        __builtin_amdgcn_s_setprio(1);
#pragma unroll
        for (int mt = 0; mt < 2; ++mt)
#pragma unroll
            for (int ct = 0; ct < 4; ++ct) {
                float4v a = (float4v){0.f, 0.f, 0.f, 0.f};
                a = __builtin_amdgcn_mfma_f32_16x16x32_bf16(kf[ct][0], qa[mt][0], a, 0, 0, 0);
                a = __builtin_amdgcn_mfma_f32_16x16x32_bf16(kf[ct][1], qa[mt][1], a, 0, 0, 0);
                s[mt][ct] = a;
            }
        __builtin_amdgcn_s_setprio(0);

        // B-frag under remap: slot q*8+e holds V[key = 32kc+16(e>>2)+4q+(e&3)]
        short8 vf[4][2];
#pragma unroll
        for (int nt = 0; nt < 4; ++nt) {
            const int rb = (nt * 16 + n) * 64;
#pragma unroll
            for (int kc = 0; kc < 2; ++kc) {
                const short4v g0 = *(const short4v*)&Vsm[cur][rb + vswz[kc][0]];
                const short4v g1 = *(const short4v*)&Vsm[cur][rb + vswz[kc][1]];
                vf[nt][kc] = __builtin_shufflevector(g0, g1, 0, 1, 2, 3, 4, 5, 6, 7);
            }
        }

#pragma unroll
        for (int mt = 0; mt < 2; ++mt) {
            // tile max for q = mt*16+n (my 16 keys, then across quads)
            float lm = s[mt][0][0];
#pragma unroll
            for (int ct = 0; ct < 4; ++ct)
#pragma unroll
                for (int r = 0; r < 4; ++r)
                    lm = fmaxf(lm, s[mt][ct][r]);
            lm = fmaxf(lm, __shfl_xor(lm, 16, 64));
            lm = fmaxf(lm, __shfl_xor(lm, 32, 64));

            const bool ev = lm > mrow[mt] + 8.0f;   // defer-max threshold
            if (__any(ev)) {
                const float mnew  = ev ? lm : mrow[mt];
                const float alpha = fexp2(mrow[mt] - mnew);  // 1.0 when !ev
                mrow[mt] = mnew;
                lrow[mt] *= alpha;
                const int ai = __float_as_int(alpha);
                float av[4];
#pragma unroll
                for (int r = 0; r < 4; ++r)
                    av[r] = __int_as_float(
                        __builtin_amdgcn_ds_bpermute(4 * (quad * 4 + r), ai));
#pragma unroll
                for (int nt = 0; nt < 4; ++nt)
#pragma unroll
                    for (int r = 0; r < 4; ++r) O[mt][nt][r] *= av[r];
            }

            // P = 2^(s - m); l as local partial (reduced once at the end)
            float pv[4][4];
            float lsum = 0.f;
#pragma unroll
            for (int ct = 0; ct < 4; ++ct)
#pragma unroll
                for (int r = 0; r < 4; ++r) {
                    const float p = fexp2(s[mt][ct][r] - mrow[mt]);
                    pv[ct][r] = p;
                    lsum += p;
                }
            lrow[mt] += lsum;

            // PV A-frag is PURELY LOCAL under the remap:
            // element e of pk[kc] = pv[2kc + (e>>2)][e&3]; cvt_pk = 1 instr.
            union { unsigned u[4]; short8 s8; } pk[2];
#pragma unroll
            for (int kc = 0; kc < 2; ++kc) {
                pk[kc].u[0] = cvtpk_bf16(pv[2 * kc][0],     pv[2 * kc][1]);
                pk[kc].u[1] = cvtpk_bf16(pv[2 * kc][2],     pv[2 * kc][3]);
                pk[kc].u[2] = cvtpk_bf16(pv[2 * kc + 1][0], pv[2 * kc + 1][1]);
                pk[kc].u[3] = cvtpk_bf16(pv[2 * kc + 1][2], pv[2 * kc + 1][3]);
            }

            __builtin_amdgcn_s_setprio(1);
#pragma unroll
            for (int nt = 0; nt < 4; ++nt) {
                O[mt][nt] = __builtin_amdgcn_mfma_f32_16x16x32_bf16(pk[0].s8, vf[nt][0], O[mt][nt], 0, 0, 0);
                O[mt][nt] = __builtin_amdgcn_mfma_f32_16x16x32_bf16(pk[1].s8, vf[nt][1], O[mt][nt], 0, 0, 0);
            }
            __builtin_amdgcn_s_setprio(0);
        }
    }

#pragma unroll
    for (int mt = 0; mt < 2; ++mt) {
        float ls = lrow[mt];
        ls += __shfl_xor(ls, 16, 64);
        ls += __shfl_xor(ls, 32, 64);
        const float linv = 1.f / ls;            // at lane: q = mt*16 + n
        const int  li = __float_as_int(linv);
        float lv[4];
#pragma unroll
        for (int r = 0; r < 4; ++r)
            lv[r] = __int_as_float(
                __builtin_amdgcn_ds_bpermute(4 * (quad * 4 + r), li));
#pragma unroll
        for (int nt = 0; nt < 4; ++nt)
#pragma unroll
            for (int r = 0; r < 4; ++r) {
                const int q = qbase + mt * 16 + quad * 4 + r;
                Yh[((size_t)(b * S_DIM + q) << 10) + h * DH + nt * 16 + n] =
                    f2bf(O[mt][nt][r] * lv[r]);
            }
    }
}

// ---------------------------------------------------------------------------
extern "C" void kernel_launch(void* const* d_in, const int* in_sizes, int n_in,
                              void* d_out, int out_size, void* d_ws, size_t ws_size,
                              hipStream_t stream)
{
    const float* x  = (const float*)d_in[0];
    const float* wq = (const float*)d_in[1];
    const float* wk = (const float*)d_in[2];
    const float* wv = (const float*)d_in[3];
    const float* wo = (const float*)d_in[4];
    const float* bo = (const float*)d_in[5];
    float* out = (float*)d_out;

    const size_t MD = (size_t)M_DIM * D_DIM;      // 4M elements
    const size_t WD = (size_t)D_DIM * D_DIM;      // 1M elements
    ushort* xh  = (ushort*)d_ws;      // 8 MB  [M,K] bf16
    ushort* Wh  = xh + MD;            // 6 MB  [3072,1024] bf16 (wq|wk|wv)
    ushort* Woh = Wh + 3 * WD;        // 2 MB  [1024,1024] bf16
    ushort* Qh  = Woh + WD;           // 8 MB  [B,H,S,Dh] bf16 (pre-scaled)
    ushort* Kh  = Qh + MD;            // 8 MB  [B,H,S,Dh] bf16
    ushort* Vt  = Kh + MD;            // 8 MB  [B,H,Dh,S] bf16
    ushort* Yh  = Vt + MD;            // 8 MB  [M,D] bf16
    if (ws_size < 48u * 1024u * 1024u) return;

    dim3 blk(256);
    cast_all<<<dim3(8192), blk, 0, stream>>>(x, wq, wk, wv, wo, xh);

    gemm_bf16<<<dim3(24, 32), blk, 0, stream>>>(xh, Wh, Qh, Kh, Vt);
    attn_mfma<<<dim3(512), blk, 0, stream>>>(Qh, Kh, Vt, Yh);
    gemm_out<<<dim3(16, 32), blk, 0, stream>>>(Yh, Woh, out, bo);
}

// Round 12
// 202.776 us; speedup vs baseline: 1.1309x; 1.0248x over previous
//
#include <hip/hip_runtime.h>
#include <math.h>

#define B_DIM 2
#define S_DIM 2048
#define D_DIM 1024
#define H_NUM 16
#define DH    64
#define M_DIM (B_DIM * S_DIM) /* 4096 */

typedef __attribute__((ext_vector_type(8))) short short8;
typedef __attribute__((ext_vector_type(4))) short short4v;
typedef __attribute__((ext_vector_type(4))) float float4v;
typedef __attribute__((ext_vector_type(4))) unsigned short ushort4v;
typedef unsigned short ushort;

static __device__ __forceinline__ ushort f2bf(float f) {
    unsigned u = __float_as_uint(f);
    u += 0x7fffu + ((u >> 16) & 1u);
    return (ushort)(u >> 16);
}

static __device__ __forceinline__ float fexp2(float x) {
#if __has_builtin(__builtin_amdgcn_exp2f)
    return __builtin_amdgcn_exp2f(x);
#else
    return exp2f(x);
#endif
}

// 2 f32 -> 2 bf16 in one u32, lo half = first arg (proven: rounds 3/4
// bit-identical).
static __device__ __forceinline__ unsigned cvtpk_bf16(float lo, float hi) {
    unsigned r;
    asm("v_cvt_pk_bf16_f32 %0, %1, %2" : "=v"(r) : "v"(lo), "v"(hi));
    return r;
}

static __device__ __forceinline__ void gload_lds16(const void* g, void* l) {
    __builtin_amdgcn_global_load_lds(
        (const __attribute__((address_space(1))) void*)g,
        (__attribute__((address_space(3))) void*)l, 16, 0, 0);
}

// ---------------------------------------------------------------------------
// Fused fp32 -> bf16 cast of ALL five tensors in one launch.
// dst layout (contiguous in ws): xh[4M] | wq[1M] | wk[1M] | wv[1M] | wo[1M]
// ---------------------------------------------------------------------------
__global__ __launch_bounds__(256)
void cast_all(const float* __restrict__ x,  const float* __restrict__ wq,
              const float* __restrict__ wk, const float* __restrict__ wv,
              const float* __restrict__ wo, ushort* __restrict__ dst)
{
    const int i = blockIdx.x * 256 + threadIdx.x;   // 0 .. 2M-1 (float4 units)
    const float4* s;
    int off;
    if      (i < 1048576) { s = (const float4*)x;  off = 0;       }
    else if (i < 1310720) { s = (const float4*)wq; off = 1048576; }
    else if (i < 1572864) { s = (const float4*)wk; off = 1310720; }
    else if (i < 1835008) { s = (const float4*)wv; off = 1572864; }
    else                  { s = (const float4*)wo; off = 1835008; }
    const float4 v = s[i - off];
    ushort4v o;
    o[0] = f2bf(v.x); o[1] = f2bf(v.y); o[2] = f2bf(v.z); o[3] = f2bf(v.w);
    ((ushort4v*)dst)[i] = o;
}

// ---------------------------------------------------------------------------
// QKV GEMM, BK=64, DOUBLE-BUFFERED single-barrier K-loop (ported from the
// attn kernel's verified structure): stage tile t+1 during compute of tile
// t; the one barrier per step drains stage(t) AFTER a full compute phase
// has covered the HBM/L2 latency. (The old 2-barrier loop exposed the full
// load latency every K-step -- at K=1024/16 steps TLP couldn't hide it.)
// Granule-XOR LDS swizzle (pre-swizzled global source + linear gload_lds
// dst + XOR'd read offsets). XCD-aware bijective block swizzle (768=8*96).
// A:[4096,1024] bf16, B:[3072,1024] bf16 row-major.
// n>>10 selects dst: 0->Qh [B,H,S,Dh] (PRE-SCALED by 0.125*log2e),
// 1->Kh [B,H,S,Dh], 2->Vt [B,H,Dh,S]; all bf16.
// ---------------------------------------------------------------------------
__global__ __launch_bounds__(256)
void gemm_bf16(const ushort* __restrict__ A, const ushort* __restrict__ B,
               ushort* __restrict__ Qh, ushort* __restrict__ Kh,
               ushort* __restrict__ Vt)
{
    __shared__ ushort Asm[2][128 * 64];   // [buf][row][k 64], granule-swizzled
    __shared__ ushort Bsm[2][128 * 64];

    const int K = 1024;
    const int NT = 16;                                 // K-tiles
    const int lin = blockIdx.y * 24 + blockIdx.x;      // hardware linear id
    const int swz = (lin & 7) * 96 + (lin >> 3);       // bijective (768=8*96)
    const int n0 = (swz % 24) * 128;
    const int m0 = (swz / 24) * 128;
    const int t    = threadIdx.x;
    const int w    = t >> 6;
    const int lane = t & 63;
    const int n    = lane & 15;
    const int quad = lane >> 4;
    const int wm = w >> 1, wn = w & 1;

    const int l8 = lane >> 3;
    const int sg = (lane & 7) ^ l8;

    const int fswz[2] = { ((0 * 4 + quad) ^ (n & 7)) * 8,
                          ((1 * 4 + quad) ^ (n & 7)) * 8 };

    float4v acc[4][4];
#pragma unroll
    for (int mt = 0; mt < 4; ++mt)
#pragma unroll
        for (int nt = 0; nt < 4; ++nt) acc[mt][nt] = (float4v){0.f, 0.f, 0.f, 0.f};

    // prologue: stage tile 0 into buffer 0
#pragma unroll
    for (int i = 0; i < 4; ++i) {
        gload_lds16(&A[(size_t)(m0 + w * 32 + i * 8 + l8) * K + sg * 8],
                    &Asm[0][(w * 32 + i * 8) * 64]);
        gload_lds16(&B[(size_t)(n0 + w * 32 + i * 8 + l8) * K + sg * 8],
                    &Bsm[0][(w * 32 + i * 8) * 64]);
    }

    for (int kt6 = 0; kt6 < NT; ++kt6) {
        __syncthreads();   // stage(kt6) complete; buf cur^1 free for overwrite
        const int cur = kt6 & 1;
        if (kt6 + 1 < NT) {
            const int kt1 = (kt6 + 1) * 64;
            const int nxt = cur ^ 1;
#pragma unroll
            for (int i = 0; i < 4; ++i) {
                gload_lds16(&A[(size_t)(m0 + w * 32 + i * 8 + l8) * K + kt1 + sg * 8],
                            &Asm[nxt][(w * 32 + i * 8) * 64]);
                gload_lds16(&B[(size_t)(n0 + w * 32 + i * 8 + l8) * K + kt1 + sg * 8],
                            &Bsm[nxt][(w * 32 + i * 8) * 64]);
            }
        }

        short8 af[4][2], bfr[4][2];
#pragma unroll
        for (int mt = 0; mt < 4; ++mt)
#pragma unroll
            for (int kk = 0; kk < 2; ++kk)
                af[mt][kk] = *(const short8*)&Asm[cur][(wm * 64 + mt * 16 + n) * 64 + fswz[kk]];
#pragma unroll
        for (int nt = 0; nt < 4; ++nt)
#pragma unroll
            for (int kk = 0; kk < 2; ++kk)
                bfr[nt][kk] = *(const short8*)&Bsm[cur][(wn * 64 + nt * 16 + n) * 64 + fswz[kk]];

        __builtin_amdgcn_s_setprio(1);
#pragma unroll
        for (int mt = 0; mt < 4; ++mt)
#pragma unroll
            for (int nt = 0; nt < 4; ++nt) {
                acc[mt][nt] = __builtin_amdgcn_mfma_f32_16x16x32_bf16(
                    af[mt][0], bfr[nt][0], acc[mt][nt], 0, 0, 0);
                acc[mt][nt] = __builtin_amdgcn_mfma_f32_16x16x32_bf16(
                    af[mt][1], bfr[nt][1], acc[mt][nt], 0, 0, 0);
            }
        __builtin_amdgcn_s_setprio(0);
    }

    const int wid = n0 >> 10;           // 0=Q 1=K 2=V (constant per block)
    ushort* dstQK = (wid == 0) ? Qh : Kh;
    const float qs = (wid == 0) ? 0.1803368801f : 1.0f;  // 0.125*log2(e)
#pragma unroll
    for (int mt = 0; mt < 4; ++mt) {
        const int m = m0 + wm * 64 + mt * 16 + quad * 4;   // +r
        const int b = m >> 11, s = m & (S_DIM - 1);
#pragma unroll
        for (int nt = 0; nt < 4; ++nt) {
            const int ng = (n0 & 1023) + wn * 64 + nt * 16 + n;
            const int h = ng >> 6, d = ng & 63;
            const int bh = b * H_NUM + h;
            if (wid < 2) {
#pragma unroll
                for (int r = 0; r < 4; ++r)
                    dstQK[(((size_t)bh * S_DIM + s + r) << 6) + d] =
                        f2bf(acc[mt][nt][r] * qs);
            } else {
                ushort4v p;
#pragma unroll
                for (int r = 0; r < 4; ++r) p[r] = f2bf(acc[mt][nt][r]);
                *(ushort4v*)&Vt[(((size_t)bh * DH + d) << 11) + s] = p;
            }
        }
    }
}

// ---------------------------------------------------------------------------
// Out-projection GEMM, 128x64 tile, BK=64, double-buffered single-barrier
// loop (same structure as QKV). Grid (16,32)=512 = 2 blocks/CU; XCD swizzle
// bijective (512=8*64). A=Yh [4096,1024], B=Woh [1024,1024] bf16 row-major.
// fp32 out[m*1024+n] = acc + bias[n].
// ---------------------------------------------------------------------------
__global__ __launch_bounds__(256)
void gemm_out(const ushort* __restrict__ A, const ushort* __restrict__ B,
              float* __restrict__ Of, const float* __restrict__ bias)
{
    __shared__ ushort Asm[2][128 * 64];
    __shared__ ushort Bsm[2][64 * 64];

    const int K = 1024;
    const int NT = 16;
    const int lin = blockIdx.y * 16 + blockIdx.x;
    const int swz = (lin & 7) * 64 + (lin >> 3);       // bijective (512=8*64)
    const int n0 = (swz % 16) * 64;
    const int m0 = (swz / 16) * 128;
    const int t    = threadIdx.x;
    const int w    = t >> 6;
    const int lane = t & 63;
    const int n    = lane & 15;
    const int quad = lane >> 4;
    const int wm = w >> 1, wn = w & 1;

    const int l8 = lane >> 3;
    const int sg = (lane & 7) ^ l8;
    const int fswz[2] = { ((0 * 4 + quad) ^ (n & 7)) * 8,
                          ((1 * 4 + quad) ^ (n & 7)) * 8 };

    float4v acc[4][2];
#pragma unroll
    for (int mt = 0; mt < 4; ++mt)
#pragma unroll
        for (int nt = 0; nt < 2; ++nt) acc[mt][nt] = (float4v){0.f, 0.f, 0.f, 0.f};

    // prologue: stage tile 0 into buffer 0
#pragma unroll
    for (int i = 0; i < 4; ++i)
        gload_lds16(&A[(size_t)(m0 + w * 32 + i * 8 + l8) * K + sg * 8],
                    &Asm[0][(w * 32 + i * 8) * 64]);
#pragma unroll
    for (int i = 0; i < 2; ++i)
        gload_lds16(&B[(size_t)(n0 + w * 16 + i * 8 + l8) * K + sg * 8],
                    &Bsm[0][(w * 16 + i * 8) * 64]);

    for (int kt6 = 0; kt6 < NT; ++kt6) {
        __syncthreads();
        const int cur = kt6 & 1;
        if (kt6 + 1 < NT) {
            const int kt1 = (kt6 + 1) * 64;
            const int nxt = cur ^ 1;
#pragma unroll
            for (int i = 0; i < 4; ++i)
                gload_lds16(&A[(size_t)(m0 + w * 32 + i * 8 + l8) * K + kt1 + sg * 8],
                            &Asm[nxt][(w * 32 + i * 8) * 64]);
#pragma unroll
            for (int i = 0; i < 2; ++i)
                gload_lds16(&B[(size_t)(n0 + w * 16 + i * 8 + l8) * K + kt1 + sg * 8],
                            &Bsm[nxt][(w * 16 + i * 8) * 64]);
        }

        short8 af[4][2], bfr[2][2];
#pragma unroll
        for (int mt = 0; mt < 4; ++mt)
#pragma unroll
            for (int kk = 0; kk < 2; ++kk)
                af[mt][kk] = *(const short8*)&Asm[cur][(wm * 64 + mt * 16 + n) * 64 + fswz[kk]];
#pragma unroll
        for (int nt = 0; nt < 2; ++nt)
#pragma unroll
            for (int kk = 0; kk < 2; ++kk)
                bfr[nt][kk] = *(const short8*)&Bsm[cur][(wn * 32 + nt * 16 + n) * 64 + fswz[kk]];

        __builtin_amdgcn_s_setprio(1);
#pragma unroll
        for (int mt = 0; mt < 4; ++mt)
#pragma unroll
            for (int nt = 0; nt < 2; ++nt) {
                acc[mt][nt] = __builtin_amdgcn_mfma_f32_16x16x32_bf16(
                    af[mt][0], bfr[nt][0], acc[mt][nt], 0, 0, 0);
                acc[mt][nt] = __builtin_amdgcn_mfma_f32_16x16x32_bf16(
                    af[mt][1], bfr[nt][1], acc[mt][nt], 0, 0, 0);
            }
        __builtin_amdgcn_s_setprio(0);
    }

#pragma unroll
    for (int mt = 0; mt < 4; ++mt) {
        const int m = m0 + wm * 64 + mt * 16 + quad * 4;
#pragma unroll
        for (int nt = 0; nt < 2; ++nt) {
            const int ng = n0 + wn * 32 + nt * 16 + n;
            const float bv = bias[ng];
#pragma unroll
            for (int r = 0; r < 4; ++r)
                Of[(size_t)(m + r) * D_DIM + ng] = acc[mt][nt][r] + bv;
        }
    }
}

// ---------------------------------------------------------------------------
// MFMA flash attention: EXACT round-7/11 kernel (measured best: 69.4 us).
// 32 q-rows/wave, 4-wave blocks, grid 512. Swapped QK^T, fully LOCAL P->PV
// handoff via the k-slot->key remap slot q*8+e <-> key 32kc+16(e>>2)+4q+(e&3).
// Defer-max (THR=8, base-2); Q pre-scaled by 0.125*log2e; cvt_pk packing.
// ---------------------------------------------------------------------------
__global__ __launch_bounds__(256)
void attn_mfma(const ushort* __restrict__ Qh, const ushort* __restrict__ Kh,
               const ushort* __restrict__ Vt, ushort* __restrict__ Yh)
{
    __shared__ ushort Ksm[2][64 * 64];   // [buf][key 64][d 64] granule-swizzled
    __shared__ ushort Vsm[2][64 * 64];   // [buf][d 64][key 64] granule-swizzled

    const int w    = threadIdx.x >> 6;
    const int lane = threadIdx.x & 63;
    const int n    = lane & 15;
    const int quad = lane >> 4;

    const int wave_id = blockIdx.x * 4 + w;
    const int bh    = wave_id >> 6;          // all 4 waves of a block: same bh
    const int qbase = (wave_id & 63) * 32;
    const int b     = bh >> 4;
    const int h     = bh & (H_NUM - 1);

    const ushort* Qb = Qh + (((size_t)bh * S_DIM) << 6);
    const ushort* Kb = Kh + (((size_t)bh * S_DIM) << 6);
    const ushort* Vb = Vt + (((size_t)bh * DH) << 11);

    const int l8 = lane >> 3;
    const int sg = (lane & 7) ^ l8;

    short8 qa[2][2];   // B-frag: lane holds Q[q = mt*16+n][d = kc*32+quad*8 ..]
#pragma unroll
    for (int mt = 0; mt < 2; ++mt)
#pragma unroll
        for (int kc = 0; kc < 2; ++kc)
            qa[mt][kc] = *(const short8*)&Qb[((size_t)(qbase + mt * 16 + n) << 6) + kc * 32 + quad * 8];

    float4v O[2][4];           // O[mt][nt][r]: q = mt*16+quad*4+r, d = nt*16+n
    float   mrow[2], lrow[2];  // per-lane: q = mt*16 + n (uniform over quads)
#pragma unroll
    for (int mt = 0; mt < 2; ++mt) {
#pragma unroll
        for (int nt = 0; nt < 4; ++nt) O[mt][nt] = (float4v){0.f, 0.f, 0.f, 0.f};
        mrow[mt] = -1e30f; lrow[mt] = 0.f;
    }

    const int fswz[2] = { ((0 * 4 + quad) ^ (n & 7)) * 8,
                          ((1 * 4 + quad) ^ (n & 7)) * 8 };
    const int h4 = (quad & 1) * 4;
    const int q2 = quad >> 1;
    int vswz[2][2];
#pragma unroll
    for (int kc = 0; kc < 2; ++kc)
#pragma unroll
        for (int cc = 0; cc < 2; ++cc)
            vswz[kc][cc] = (((4 * kc + 2 * cc + q2) ^ (n & 7)) << 3) + h4;

    // prologue: stage tile 0 into buffer 0
#pragma unroll
    for (int i = 0; i < 2; ++i) {
        gload_lds16(&Kb[(size_t)(w * 16 + i * 8 + l8) * 64 + sg * 8],
                    &Ksm[0][(w * 16 + i * 8) * 64]);
        gload_lds16(&Vb[(size_t)(w * 16 + i * 8 + l8) * 2048 + sg * 8],
                    &Vsm[0][(w * 16 + i * 8) * 64]);
    }

    for (int kb = 0; kb < S_DIM / 64; ++kb) {
        __syncthreads();   // stage(kb) complete; buf cur^1 free for overwrite
        const int cur = kb & 1;
        if (kb + 1 < S_DIM / 64) {
            const int key1 = (kb + 1) * 64;
            const int nxt  = cur ^ 1;
#pragma unroll
            for (int i = 0; i < 2; ++i) {
                gload_lds16(&Kb[(size_t)(key1 + w * 16 + i * 8 + l8) * 64 + sg * 8],
                            &Ksm[nxt][(w * 16 + i * 8) * 64]);
                gload_lds16(&Vb[(size_t)(w * 16 + i * 8 + l8) * 2048 + key1 + sg * 8],
                            &Vsm[nxt][(w * 16 + i * 8) * 64]);
            }
        }

        // A-frag: lane holds K[key = ct*16+n][d = kc*32+quad*8 ..]
        short8 kf[4][2];
#pragma unroll
        for (int ct = 0; ct < 4; ++ct)
#pragma unroll
            for (int kc = 0; kc < 2; ++kc)
                kf[ct][kc] = *(const short8*)&Ksm[cur][(ct * 16 + n) * 64 + fswz[kc]];

        // S^T[key][q]: s[mt][ct][r] = S[q = mt*16+n][key = ct*16+quad*4+r]
        float4v s[2][4];
        __builtin_amdgcn_s_setprio(1);
#pragma unroll
        for (int mt = 0; mt < 2; ++mt)
#pragma unroll
            for (int ct = 0; ct < 4; ++ct) {
                float4v a = (float4v){0.f, 0.f, 0.f, 0.f};
                a = __builtin_amdgcn_mfma_f32_16x16x32_bf16(kf[ct][0], qa[mt][0], a, 0, 0, 0);
                a = __builtin_amdgcn_mfma_f32_16x16x32_bf16(kf[ct][1], qa[mt][1], a, 0, 0, 0);
                s[mt][ct] = a;
            }
        __builtin_amdgcn_s_setprio(0);

        // B-frag under remap: slot q*8+e holds V[key = 32kc+16(e>>2)+4q+(e&3)]
        short8 vf[4][2];
#pragma unroll
        for (int nt = 0; nt < 4; ++nt) {
            const int rb = (nt * 16 + n) * 64;
#pragma unroll
            for (int kc = 0; kc < 2; ++kc) {
                const short4v g0 = *(const short4v*)&Vsm[cur][rb + vswz[kc][0]];
                const short4v g1 = *(const short4v*)&Vsm[cur][rb + vswz[kc][1]];
                vf[nt][kc] = __builtin_shufflevector(g0, g1, 0, 1, 2, 3, 4, 5, 6, 7);
            }
        }

#pragma unroll
        for (int mt = 0; mt < 2; ++mt) {
            // tile max for q = mt*16+n (my 16 keys, then across quads)
            float lm = s[mt][0][0];
#pragma unroll
            for (int ct = 0; ct < 4; ++ct)
#pragma unroll
                for (int r = 0; r < 4; ++r)
                    lm = fmaxf(lm, s[mt][ct][r]);
            lm = fmaxf(lm, __shfl_xor(lm, 16, 64));
            lm = fmaxf(lm, __shfl_xor(lm, 32, 64));

            const bool ev = lm > mrow[mt] + 8.0f;   // defer-max threshold
            if (__any(ev)) {
                const float mnew  = ev ? lm : mrow[mt];
                const float alpha = fexp2(mrow[mt] - mnew);  // 1.0 when !ev
                mrow[mt] = mnew;
                lrow[mt] *= alpha;
                const int ai = __float_as_int(alpha);
                float av[4];
#pragma unroll
                for (int r = 0; r < 4; ++r)
                    av[r] = __int_as_float(
                        __builtin_amdgcn_ds_bpermute(4 * (quad * 4 + r), ai));
#pragma unroll
                for (int nt = 0; nt < 4; ++nt)
#pragma unroll
                    for (int r = 0; r < 4; ++r) O[mt][nt][r] *= av[r];
            }

            // P = 2^(s - m); l as local partial (reduced once at the end)
            float pv[4][4];
            float lsum = 0.f;
#pragma unroll
            for (int ct = 0; ct < 4; ++ct)
#pragma unroll
                for (int r = 0; r < 4; ++r) {
                    const float p = fexp2(s[mt][ct][r] - mrow[mt]);
                    pv[ct][r] = p;
                    lsum += p;
                }
            lrow[mt] += lsum;

            // PV A-frag is PURELY LOCAL under the remap:
            // element e of pk[kc] = pv[2kc + (e>>2)][e&3]; cvt_pk = 1 instr.
            union { unsigned u[4]; short8 s8; } pk[2];
#pragma unroll
            for (int kc = 0; kc < 2; ++kc) {
                pk[kc].u[0] = cvtpk_bf16(pv[2 * kc][0],     pv[2 * kc][1]);
                pk[kc].u[1] = cvtpk_bf16(pv[2 * kc][2],     pv[2 * kc][3]);
                pk[kc].u[2] = cvtpk_bf16(pv[2 * kc + 1][0], pv[2 * kc + 1][1]);
                pk[kc].u[3] = cvtpk_bf16(pv[2 * kc + 1][2], pv[2 * kc + 1][3]);
            }

            __builtin_amdgcn_s_setprio(1);
#pragma unroll
            for (int nt = 0; nt < 4; ++nt) {
                O[mt][nt] = __builtin_amdgcn_mfma_f32_16x16x32_bf16(pk[0].s8, vf[nt][0], O[mt][nt], 0, 0, 0);
                O[mt][nt] = __builtin_amdgcn_mfma_f32_16x16x32_bf16(pk[1].s8, vf[nt][1], O[mt][nt], 0, 0, 0);
            }
            __builtin_amdgcn_s_setprio(0);
        }
    }

#pragma unroll
    for (int mt = 0; mt < 2; ++mt) {
        float ls = lrow[mt];
        ls += __shfl_xor(ls, 16, 64);
        ls += __shfl_xor(ls, 32, 64);
        const float linv = 1.f / ls;            // at lane: q = mt*16 + n
        const int  li = __float_as_int(linv);
        float lv[4];
#pragma unroll
        for (int r = 0; r < 4; ++r)
            lv[r] = __int_as_float(
                __builtin_amdgcn_ds_bpermute(4 * (quad * 4 + r), li));
#pragma unroll
        for (int nt = 0; nt < 4; ++nt)
#pragma unroll
            for (int r = 0; r < 4; ++r) {
                const int q = qbase + mt * 16 + quad * 4 + r;
                Yh[((size_t)(b * S_DIM + q) << 10) + h * DH + nt * 16 + n] =
                    f2bf(O[mt][nt][r] * lv[r]);
            }
    }
}

// ---------------------------------------------------------------------------
extern "C" void kernel_launch(void* const* d_in, const int* in_sizes, int n_in,
                              void* d_out, int out_size, void* d_ws, size_t ws_size,
                              hipStream_t stream)
{
    const float* x  = (const float*)d_in[0];
    const float* wq = (const float*)d_in[1];
    const float* wk = (const float*)d_in[2];
    const float* wv = (const float*)d_in[3];
    const float* wo = (const float*)d_in[4];
    const float* bo = (const float*)d_in[5];
    float* out = (float*)d_out;

    const size_t MD = (size_t)M_DIM * D_DIM;      // 4M elements
    const size_t WD = (size_t)D_DIM * D_DIM;      // 1M elements
    ushort* xh  = (ushort*)d_ws;      // 8 MB  [M,K] bf16
    ushort* Wh  = xh + MD;            // 6 MB  [3072,1024] bf16 (wq|wk|wv)
    ushort* Woh = Wh + 3 * WD;        // 2 MB  [1024,1024] bf16
    ushort* Qh  = Woh + WD;           // 8 MB  [B,H,S,Dh] bf16 (pre-scaled)
    ushort* Kh  = Qh + MD;            // 8 MB  [B,H,S,Dh] bf16
    ushort* Vt  = Kh + MD;            // 8 MB  [B,H,Dh,S] bf16
    ushort* Yh  = Vt + MD;            // 8 MB  [M,D] bf16
    if (ws_size < 48u * 1024u * 1024u) return;

    dim3 blk(256);
    cast_all<<<dim3(8192), blk, 0, stream>>>(x, wq, wk, wv, wo, xh);

    gemm_bf16<<<dim3(24, 32), blk, 0, stream>>>(xh, Wh, Qh, Kh, Vt);
    attn_mfma<<<dim3(512), blk, 0, stream>>>(Qh, Kh, Vt, Yh);
    gemm_out<<<dim3(16, 32), blk, 0, stream>>>(Yh, Woh, out, bo);
}